// Round 1
// baseline (33845.078 us; speedup 1.0000x reference)
//
#include <hip/hip_runtime.h>
#include <stdint.h>

#define BQ 16      // batch
#define TT 4096    // timesteps
#define II 128     // input features
#define HH 256     // hidden
#define G4 1024    // 4*H

__device__ __forceinline__ float sigmoidf_(float x) { return 1.0f / (1.0f + __expf(-x)); }

// C[m][n] = sum_k A_row(m)[k] * W[n][k] + bias[n]
// A row address: b = m>>tcShift, t = m&mask ->  A + b*aBatch + (t0+t)*aT
template<int K>
__global__ __launch_bounds__(256, 2)
void gemm_xw(const float* __restrict__ A, const float* __restrict__ W,
             const float* __restrict__ bias, float* __restrict__ C,
             size_t aBatch, int aT, int t0, int tcShift)
{
    __shared__ float As[128][17];
    __shared__ float Ws[128][17];
    const int tid = threadIdx.x;
    const int tx = tid & 15, ty = tid >> 4;
    const int n0 = blockIdx.x * 128;
    const int m0 = blockIdx.y * 128;
    const int mask = (1 << tcShift) - 1;

    float acc[8][8];
#pragma unroll
    for (int i = 0; i < 8; i++)
#pragma unroll
        for (int j = 0; j < 8; j++) acc[i][j] = 0.f;

    const int lr = tid >> 1;           // 0..127
    const int lk = (tid & 1) * 8;      // 0 or 8
    const int rA = m0 + lr;
    const size_t aRow = (size_t)(rA >> tcShift) * aBatch + (size_t)(t0 + (rA & mask)) * (size_t)aT;
    const size_t wRow = (size_t)(n0 + lr) * (size_t)K;

    for (int k0 = 0; k0 < K; k0 += 16) {
        float4 a0 = *(const float4*)(A + aRow + k0 + lk);
        float4 a1 = *(const float4*)(A + aRow + k0 + lk + 4);
        float4 w0 = *(const float4*)(W + wRow + k0 + lk);
        float4 w1 = *(const float4*)(W + wRow + k0 + lk + 4);
        As[lr][lk+0]=a0.x; As[lr][lk+1]=a0.y; As[lr][lk+2]=a0.z; As[lr][lk+3]=a0.w;
        As[lr][lk+4]=a1.x; As[lr][lk+5]=a1.y; As[lr][lk+6]=a1.z; As[lr][lk+7]=a1.w;
        Ws[lr][lk+0]=w0.x; Ws[lr][lk+1]=w0.y; Ws[lr][lk+2]=w0.z; Ws[lr][lk+3]=w0.w;
        Ws[lr][lk+4]=w1.x; Ws[lr][lk+5]=w1.y; Ws[lr][lk+6]=w1.z; Ws[lr][lk+7]=w1.w;
        __syncthreads();
#pragma unroll
        for (int kk = 0; kk < 16; kk++) {
            float av[8], wv[8];
#pragma unroll
            for (int i = 0; i < 8; i++) av[i] = As[ty*8+i][kk];
#pragma unroll
            for (int j = 0; j < 8; j++) wv[j] = Ws[tx*8+j][kk];
#pragma unroll
            for (int i = 0; i < 8; i++)
#pragma unroll
                for (int j = 0; j < 8; j++) acc[i][j] = fmaf(av[i], wv[j], acc[i][j]);
        }
        __syncthreads();
    }
    float bv[8];
#pragma unroll
    for (int j = 0; j < 8; j++) bv[j] = bias[n0 + tx*8 + j];
#pragma unroll
    for (int i = 0; i < 8; i++) {
        const int m = m0 + ty*8 + i;
        float* cp = C + (size_t)m * G4 + n0 + tx*8;
#pragma unroll
        for (int j = 0; j < 8; j++) cp[j] = acc[i][j] + bv[j];
    }
}

// One LSTM layer scan over a chunk of TC timesteps.
// Grid: (4, BQ). Each WG owns 64 h-elements (j in [g*64, g*64+64)) of one batch:
// gate rows {j, 256+j, 512+j, 768+j}. Thread tid: q=tid>>6 (gate block), jl=tid&63.
// Weights for the thread's single gate row live in 256 VGPRs.
// Per-step cross-WG h exchange through hHist (global) + per-(b,t) arrival counters.
__global__ __launch_bounds__(256, 1)
void lstm_scan(const float* __restrict__ Whh, const float* __restrict__ xW,
               float* hHist, size_t hBatch, int hT0,
               float* hState, float* cState, int* count,
               int t0, int TC)
{
    const int tid = threadIdx.x;
    const int g = blockIdx.x;   // 0..3
    const int b = blockIdx.y;   // 0..15
    const int q = tid >> 6;     // gate block (wave-uniform)
    const int jl = tid & 63;
    const int j = g * 64 + jl;
    const int row = q * 256 + j;

    float4 w4[64];
    {
        const float* wr = Whh + (size_t)row * HH;
#pragma unroll
        for (int k = 0; k < 64; k++) w4[k] = *(const float4*)(wr + 4*k);
    }

    __shared__ __align__(16) float h_lds[HH];
    __shared__ float gates[256];

    float c_reg = 0.f;
    if (tid < 64) c_reg = cState[b*HH + g*64 + tid];

    for (int t = 0; t < TC; t++) {
        const int tg = t0 + t;
        if (t == 0) {
            if (tid < 64) {
                float4 hv = *(const float4*)(hState + b*HH + tid*4);
                *(float4*)&h_lds[tid*4] = hv;
            }
        } else {
            if (tid == 0) {
                while (__hip_atomic_load(&count[(size_t)b*TT + tg - 1],
                                         __ATOMIC_ACQUIRE, __HIP_MEMORY_SCOPE_AGENT) < 4) {
                    __builtin_amdgcn_s_sleep(1);
                }
            }
            __syncthreads();
            if (tid < 64) {
                float* hp = hHist + (size_t)b*hBatch + (size_t)(hT0 + t - 1) * HH + tid*4;
                float v0 = __hip_atomic_load(hp+0, __ATOMIC_RELAXED, __HIP_MEMORY_SCOPE_AGENT);
                float v1 = __hip_atomic_load(hp+1, __ATOMIC_RELAXED, __HIP_MEMORY_SCOPE_AGENT);
                float v2 = __hip_atomic_load(hp+2, __ATOMIC_RELAXED, __HIP_MEMORY_SCOPE_AGENT);
                float v3 = __hip_atomic_load(hp+3, __ATOMIC_RELAXED, __HIP_MEMORY_SCOPE_AGENT);
                h_lds[tid*4+0]=v0; h_lds[tid*4+1]=v1; h_lds[tid*4+2]=v2; h_lds[tid*4+3]=v3;
            }
        }
        __syncthreads();

        const float xv = xW[((size_t)b*TC + t) * G4 + row];
        float acc = 0.f;
#pragma unroll
        for (int k = 0; k < 64; k++) {
            float4 hv = *(const float4*)&h_lds[4*k];
            acc = fmaf(w4[k].x, hv.x, acc);
            acc = fmaf(w4[k].y, hv.y, acc);
            acc = fmaf(w4[k].z, hv.z, acc);
            acc = fmaf(w4[k].w, hv.w, acc);
        }
        const float pre = acc + xv;
        gates[tid] = (q == 2) ? tanhf(pre) : sigmoidf_(pre);
        __syncthreads();

        if (tid < 64) {
            const float iv = gates[tid];
            const float fv = gates[64 + tid];
            const float gv = gates[128 + tid];
            const float ov = gates[192 + tid];
            c_reg = fmaf(fv, c_reg, iv * gv);
            const float hv = ov * tanhf(c_reg);
            float* hp = hHist + (size_t)b*hBatch + (size_t)(hT0 + t) * HH + g*64 + tid;
            __hip_atomic_store(hp, hv, __ATOMIC_RELAXED, __HIP_MEMORY_SCOPE_AGENT);
            if (t == TC - 1) {
                hState[b*HH + g*64 + tid] = hv;
                cState[b*HH + g*64 + tid] = c_reg;
            }
        }
        __syncthreads();
        if (tid == 0) {
            __hip_atomic_fetch_add(&count[(size_t)b*TT + tg], 1,
                                   __ATOMIC_RELEASE, __HIP_MEMORY_SCOPE_AGENT);
        }
    }
}

extern "C" void kernel_launch(void* const* d_in, const int* in_sizes, int n_in,
                              void* d_out, int out_size, void* d_ws, size_t ws_size,
                              hipStream_t stream) {
    const float* x    = (const float*)d_in[0];
    const float* Wih0 = (const float*)d_in[1];
    const float* Whh0 = (const float*)d_in[2];
    const float* b0   = (const float*)d_in[3];
    const float* Wih1 = (const float*)d_in[4];
    const float* Whh1 = (const float*)d_in[5];
    const float* b1   = (const float*)d_in[6];
    float* out = (float*)d_out;

    // ---- workspace carve ----
    char* ws = (char*)d_ws;
    float* h0s = (float*)ws;                 // [16][256]
    float* c0s = h0s + BQ*HH;
    float* h2s = c0s + BQ*HH;
    float* c1s = h2s + BQ*HH;
    int*   cnt0 = (int*)(c1s + BQ*HH);       // [16][4096]
    int*   cnt1 = cnt0 + BQ*TT;
    float* bulk = (float*)(cnt1 + BQ*TT);
    const size_t fixedBytes = (size_t)((char*)bulk - ws);

    // choose largest chunk TC (power of two) fitting workspace
    int TC = 4096;
    while (TC > 64 && fixedBytes + (size_t)BQ * TC * (HH + G4) * 4 > ws_size) TC >>= 1;
    const int tcShift = __builtin_ctz((unsigned)TC);

    float* h1c = bulk;                        // [16][TC][256]
    float* xWb = h1c + (size_t)BQ*TC*HH;      // [16][TC][1024]

    // zero states + counters (once per launch; graph-capture safe)
    hipMemsetAsync(ws, 0, fixedBytes, stream);

    for (int t0 = 0; t0 < TT; t0 += TC) {
        // xW0 chunk = x @ Wih0^T + b0
        dim3 g0(G4/128, (BQ*TC)/128);
        gemm_xw<II><<<g0, 256, 0, stream>>>(x, Wih0, b0, xWb,
                                            (size_t)TT*II, II, t0, tcShift);
        // layer-0 scan over chunk -> h1c
        lstm_scan<<<dim3(4, BQ), 256, 0, stream>>>(Whh0, xWb, h1c,
                                                   (size_t)TC*HH, 0,
                                                   h0s, c0s, cnt0, t0, TC);
        // xW1 chunk = h1c @ Wih1^T + b1 (reuses xWb)
        dim3 g1(G4/128, (BQ*TC)/128);
        gemm_xw<HH><<<g1, 256, 0, stream>>>(h1c, Wih1, b1, xWb,
                                            (size_t)TC*HH, HH, 0, tcShift);
        // layer-1 scan over chunk -> d_out
        lstm_scan<<<dim3(4, BQ), 256, 0, stream>>>(Whh1, xWb, out,
                                                   (size_t)TT*HH, t0,
                                                   h2s, c1s, cnt1, t0, TC);
    }
}

// Round 2
// 31152.704 us; speedup vs baseline: 1.0864x; 1.0864x over previous
//
#include <hip/hip_runtime.h>
#include <stdint.h>

#define BQ 16      // batch
#define TT 4096    // timesteps
#define II 128     // input features
#define HH 256     // hidden
#define G4 1024    // 4*H

__device__ __forceinline__ float sigmoidf_(float x) { return 1.0f / (1.0f + __expf(-x)); }

// C[m][n] = sum_k A_row(m)[k] * W[n][k] + bias[n]
// A row address: b = m>>tcShift, t = m&mask ->  A + b*aBatch + (t0+t)*aT
template<int K>
__global__ __launch_bounds__(256, 2)
void gemm_xw(const float* __restrict__ A, const float* __restrict__ W,
             const float* __restrict__ bias, float* __restrict__ C,
             size_t aBatch, int aT, int t0, int tcShift)
{
    __shared__ float As[128][17];
    __shared__ float Ws[128][17];
    const int tid = threadIdx.x;
    const int tx = tid & 15, ty = tid >> 4;
    const int n0 = blockIdx.x * 128;
    const int m0 = blockIdx.y * 128;
    const int mask = (1 << tcShift) - 1;

    float acc[8][8];
#pragma unroll
    for (int i = 0; i < 8; i++)
#pragma unroll
        for (int j = 0; j < 8; j++) acc[i][j] = 0.f;

    const int lr = tid >> 1;           // 0..127
    const int lk = (tid & 1) * 8;      // 0 or 8
    const int rA = m0 + lr;
    const size_t aRow = (size_t)(rA >> tcShift) * aBatch + (size_t)(t0 + (rA & mask)) * (size_t)aT;
    const size_t wRow = (size_t)(n0 + lr) * (size_t)K;

    for (int k0 = 0; k0 < K; k0 += 16) {
        float4 a0 = *(const float4*)(A + aRow + k0 + lk);
        float4 a1 = *(const float4*)(A + aRow + k0 + lk + 4);
        float4 w0 = *(const float4*)(W + wRow + k0 + lk);
        float4 w1 = *(const float4*)(W + wRow + k0 + lk + 4);
        As[lr][lk+0]=a0.x; As[lr][lk+1]=a0.y; As[lr][lk+2]=a0.z; As[lr][lk+3]=a0.w;
        As[lr][lk+4]=a1.x; As[lr][lk+5]=a1.y; As[lr][lk+6]=a1.z; As[lr][lk+7]=a1.w;
        Ws[lr][lk+0]=w0.x; Ws[lr][lk+1]=w0.y; Ws[lr][lk+2]=w0.z; Ws[lr][lk+3]=w0.w;
        Ws[lr][lk+4]=w1.x; Ws[lr][lk+5]=w1.y; Ws[lr][lk+6]=w1.z; Ws[lr][lk+7]=w1.w;
        __syncthreads();
#pragma unroll
        for (int kk = 0; kk < 16; kk++) {
            float av[8], wv[8];
#pragma unroll
            for (int i = 0; i < 8; i++) av[i] = As[ty*8+i][kk];
#pragma unroll
            for (int j = 0; j < 8; j++) wv[j] = Ws[tx*8+j][kk];
#pragma unroll
            for (int i = 0; i < 8; i++)
#pragma unroll
                for (int j = 0; j < 8; j++) acc[i][j] = fmaf(av[i], wv[j], acc[i][j]);
        }
        __syncthreads();
    }
    float bv[8];
#pragma unroll
    for (int j = 0; j < 8; j++) bv[j] = bias[n0 + tx*8 + j];
#pragma unroll
    for (int i = 0; i < 8; i++) {
        const int m = m0 + ty*8 + i;
        float* cp = C + (size_t)m * G4 + n0 + tx*8;
#pragma unroll
        for (int j = 0; j < 8; j++) cp[j] = acc[i][j] + bv[j];
    }
}

// Fused two-layer pipelined scan.
// Grid: (12, BQ). blockIdx.x 0..3 = layer-0 WG g; 4..11 = layer-1 WG w.
// Layer 0 (per batch, 4 WGs x 256 thr): WG g owns h1 elems [g*64,g*64+64);
//   thread owns gate row q*256+g*64+jl, 256 weights (Whh0 row) in VGPRs.
//   gates0 = Whh0 @ h1_{t-1} + xW0[t]   (xW0 precomputed by gemm_xw).
// Layer 1 (per batch, 8 WGs x 256 thr): WG w owns h2 elems [w*32,w*32+32)
//   = 128 gate rows, 2 threads/row: A-thread (tid<128) Whh1 row (K=256 over
//   h2_{t-1}), B-thread Wih1 row (K=256 over h1_t). Pair-reduce via LDS.
// Handshake: write-once flags per (b,t,producer); consumers poll lane-parallel
// with acquire loads; data via relaxed agent-scope loads/stores.
__global__ __launch_bounds__(256, 1)
void lstm_fused(const float* __restrict__ Whh0, const float* __restrict__ Whh1,
                const float* __restrict__ Wih1, const float* __restrict__ b1,
                const float* __restrict__ xW,   // [BQ][TC][G4] chunk-local
                float* h1buf,                   // [BQ][TC][HH] chunk-local
                float* out,                     // [BQ][TT][HH] (h2 history)
                float* h1s, float* c0s, float* h2s, float* c1s,
                int* f0, int* f1,               // [BQ][TT][4], [BQ][TT][8]
                int t0, int TC)
{
    const int tid = threadIdx.x;
    const int b = blockIdx.y;
    __shared__ __align__(16) float hA[HH];   // h1_prev (L0) / h2_prev (L1)
    __shared__ __align__(16) float hB[HH];   // h1_cur (L1)
    __shared__ float part[128];
    __shared__ float gates[256];

    if (blockIdx.x < 4) {
        // ------------------------- layer 0 -------------------------
        const int g = blockIdx.x;
        const int q = tid >> 6;
        const int jl = tid & 63;
        const int row = q * 256 + g * 64 + jl;
        float4 w4[64];
        {
            const float* wr = Whh0 + (size_t)row * HH;
#pragma unroll
            for (int k = 0; k < 64; k++) w4[k] = *(const float4*)(wr + 4*k);
        }
        float c_reg = (tid < 64) ? c0s[b*HH + g*64 + tid] : 0.f;

        for (int t = 0; t < TC; t++) {
            const int gt = t0 + t;
            const float xv = xW[((size_t)b*TC + t) * G4 + row];
            if (tid < 64) {
                if (t == 0) {
                    *(float4*)&hA[tid*4] = *(const float4*)(h1s + b*HH + tid*4);
                } else {
                    const int* fp = f0 + ((size_t)b*TT + (gt-1)) * 4;
                    int ok;
                    do {
                        int v = (tid < 4) ? __hip_atomic_load(fp + tid, __ATOMIC_ACQUIRE, __HIP_MEMORY_SCOPE_AGENT) : 1;
                        ok = __all(v != 0);
                        if (!ok) __builtin_amdgcn_s_sleep(1);
                    } while (!ok);
                    const float* hp = h1buf + ((size_t)b*TC + (t-1)) * HH;
#pragma unroll
                    for (int k = 0; k < 4; k++)
                        hA[tid*4+k] = __hip_atomic_load(hp + tid*4 + k, __ATOMIC_RELAXED, __HIP_MEMORY_SCOPE_AGENT);
                }
            }
            __syncthreads();
            float ac0=0.f, ac1=0.f, ac2=0.f, ac3=0.f;
#pragma unroll
            for (int k = 0; k < 64; k++) {
                float4 hv = *(const float4*)&hA[4*k];
                ac0 = fmaf(w4[k].x, hv.x, ac0);
                ac1 = fmaf(w4[k].y, hv.y, ac1);
                ac2 = fmaf(w4[k].z, hv.z, ac2);
                ac3 = fmaf(w4[k].w, hv.w, ac3);
            }
            const float pre = (ac0 + ac1) + (ac2 + ac3) + xv;
            gates[tid] = (q == 2) ? tanhf(pre) : sigmoidf_(pre);
            __syncthreads();
            if (tid < 64) {
                const float iv = gates[tid];
                const float fv = gates[64 + tid];
                const float gv = gates[128 + tid];
                const float ov = gates[192 + tid];
                c_reg = fmaf(fv, c_reg, iv * gv);
                const float hv = ov * tanhf(c_reg);
                __hip_atomic_store(h1buf + ((size_t)b*TC + t)*HH + g*64 + tid, hv,
                                   __ATOMIC_RELAXED, __HIP_MEMORY_SCOPE_AGENT);
                if (t == TC - 1) {
                    h1s[b*HH + g*64 + tid] = hv;
                    c0s[b*HH + g*64 + tid] = c_reg;
                }
                if (tid == 0)
                    __hip_atomic_store(f0 + ((size_t)b*TT + gt)*4 + g, 1,
                                       __ATOMIC_RELEASE, __HIP_MEMORY_SCOPE_AGENT);
            }
        }
    } else {
        // ------------------------- layer 1 -------------------------
        const int w = blockIdx.x - 4;     // 0..7
        const int r = tid & 127;          // row within WG's 128
        const int isB = tid >> 7;         // 0: Whh1 (h2 part), 1: Wih1 (h1 part)
        const int q = r >> 5, jl = r & 31;
        const int row = q * 256 + w * 32 + jl;
        float4 w4[64];
        {
            const float* wr = (isB ? Wih1 : Whh1) + (size_t)row * HH;
#pragma unroll
            for (int k = 0; k < 64; k++) w4[k] = *(const float4*)(wr + 4*k);
        }
        const float bias = b1[row];
        float c_reg = (tid < 32) ? c1s[b*HH + w*32 + tid] : 0.f;

        for (int t = 0; t < TC; t++) {
            const int gt = t0 + t;
            if (tid < 64) {
                // wave 0: stage h2_{t-1}
                if (t == 0) {
                    *(float4*)&hA[tid*4] = *(const float4*)(h2s + b*HH + tid*4);
                } else {
                    const int* fp = f1 + ((size_t)b*TT + (gt-1)) * 8;
                    int ok;
                    do {
                        int v = (tid < 8) ? __hip_atomic_load(fp + tid, __ATOMIC_ACQUIRE, __HIP_MEMORY_SCOPE_AGENT) : 1;
                        ok = __all(v != 0);
                        if (!ok) __builtin_amdgcn_s_sleep(1);
                    } while (!ok);
                    const float* hp = out + ((size_t)b*TT + (gt-1)) * HH;
#pragma unroll
                    for (int k = 0; k < 4; k++)
                        hA[tid*4+k] = __hip_atomic_load(hp + tid*4 + k, __ATOMIC_RELAXED, __HIP_MEMORY_SCOPE_AGENT);
                }
            } else if (tid < 128) {
                // wave 1: stage h1_t (produced by layer-0 this chunk)
                const int l = tid - 64;
                const int* fp = f0 + ((size_t)b*TT + gt) * 4;
                int ok;
                do {
                    int v = (l < 4) ? __hip_atomic_load(fp + l, __ATOMIC_ACQUIRE, __HIP_MEMORY_SCOPE_AGENT) : 1;
                    ok = __all(v != 0);
                    if (!ok) __builtin_amdgcn_s_sleep(1);
                } while (!ok);
                const float* hp = h1buf + ((size_t)b*TC + t) * HH;
#pragma unroll
                for (int k = 0; k < 4; k++)
                    hB[l*4+k] = __hip_atomic_load(hp + l*4 + k, __ATOMIC_RELAXED, __HIP_MEMORY_SCOPE_AGENT);
            }
            __syncthreads();
            const float* hsrc = isB ? hB : hA;
            float ac0=0.f, ac1=0.f, ac2=0.f, ac3=0.f;
#pragma unroll
            for (int k = 0; k < 64; k++) {
                float4 hv = *(const float4*)&hsrc[4*k];
                ac0 = fmaf(w4[k].x, hv.x, ac0);
                ac1 = fmaf(w4[k].y, hv.y, ac1);
                ac2 = fmaf(w4[k].z, hv.z, ac2);
                ac3 = fmaf(w4[k].w, hv.w, ac3);
            }
            const float dot = (ac0 + ac1) + (ac2 + ac3);
            if (isB) part[r] = dot;
            __syncthreads();
            if (!isB) {
                const float pre = dot + part[r] + bias;
                gates[r] = (q == 2) ? tanhf(pre) : sigmoidf_(pre);
            }
            __syncthreads();
            if (tid < 32) {
                const float iv = gates[tid];
                const float fv = gates[32 + tid];
                const float gv = gates[64 + tid];
                const float ov = gates[96 + tid];
                c_reg = fmaf(fv, c_reg, iv * gv);
                const float hv = ov * tanhf(c_reg);
                __hip_atomic_store(out + ((size_t)b*TT + gt)*HH + w*32 + tid, hv,
                                   __ATOMIC_RELAXED, __HIP_MEMORY_SCOPE_AGENT);
                if (t == TC - 1) {
                    h2s[b*HH + w*32 + tid] = hv;
                    c1s[b*HH + w*32 + tid] = c_reg;
                }
                if (tid == 0)
                    __hip_atomic_store(f1 + ((size_t)b*TT + gt)*8 + w, 1,
                                       __ATOMIC_RELEASE, __HIP_MEMORY_SCOPE_AGENT);
            }
        }
    }
}

extern "C" void kernel_launch(void* const* d_in, const int* in_sizes, int n_in,
                              void* d_out, int out_size, void* d_ws, size_t ws_size,
                              hipStream_t stream) {
    const float* x    = (const float*)d_in[0];
    const float* Wih0 = (const float*)d_in[1];
    const float* Whh0 = (const float*)d_in[2];
    const float* b0   = (const float*)d_in[3];
    const float* Wih1 = (const float*)d_in[4];
    const float* Whh1 = (const float*)d_in[5];
    const float* b1   = (const float*)d_in[6];
    float* out = (float*)d_out;

    // ---- workspace carve ----
    char* ws = (char*)d_ws;
    float* h1s = (float*)ws;                 // [16][256]
    float* c0s = h1s + BQ*HH;
    float* h2s = c0s + BQ*HH;
    float* c1s = h2s + BQ*HH;
    int*   f0  = (int*)(c1s + BQ*HH);        // [16][4096][4]
    int*   f1  = f0 + (size_t)BQ*TT*4;       // [16][4096][8]
    float* bulk = (float*)(f1 + (size_t)BQ*TT*8);
    const size_t fixedBytes = (size_t)((char*)bulk - ws);

    // choose largest chunk TC (power of two) fitting workspace
    int TC = 4096;
    while (TC > 64 && fixedBytes + (size_t)BQ * TC * (HH + G4) * 4 > ws_size) TC >>= 1;
    const int tcShift = __builtin_ctz((unsigned)TC);

    float* h1buf = bulk;                      // [16][TC][256]
    float* xWb = h1buf + (size_t)BQ*TC*HH;    // [16][TC][1024]

    // zero states + flags (once per launch; graph-capture safe)
    hipMemsetAsync(ws, 0, fixedBytes, stream);

    for (int t0 = 0; t0 < TT; t0 += TC) {
        // xW0 chunk = x @ Wih0^T + b0
        dim3 g0(G4/128, (BQ*TC)/128);
        gemm_xw<II><<<g0, 256, 0, stream>>>(x, Wih0, b0, xWb,
                                            (size_t)TT*II, II, t0, tcShift);
        // fused pipelined two-layer scan over chunk
        lstm_fused<<<dim3(12, BQ), 256, 0, stream>>>(Whh0, Whh1, Wih1, b1,
                                                     xWb, h1buf, out,
                                                     h1s, c0s, h2s, c1s,
                                                     f0, f1, t0, TC);
    }
}

// Round 3
// 30554.556 us; speedup vs baseline: 1.1077x; 1.0196x over previous
//
#include <hip/hip_runtime.h>
#include <stdint.h>

#define BQ 16      // batch
#define TT 4096    // timesteps
#define II 128     // input features
#define HH 256     // hidden
#define G4 1024    // 4*H

__device__ __forceinline__ float sigmoidf_(float x) { return 1.0f / (1.0f + __expf(-x)); }

__device__ __forceinline__ void poll_ge(const int* p, int target) {
    // all lanes load the same word -> one coalesced request; uniform loop
    while (__hip_atomic_load(p, __ATOMIC_ACQUIRE, __HIP_MEMORY_SCOPE_AGENT) < target)
        __builtin_amdgcn_s_sleep(1);
}

// C[m][n] = sum_k A_row(m)[k] * W[n][k] + bias[n]
template<int K>
__global__ __launch_bounds__(256, 2)
void gemm_xw(const float* __restrict__ A, const float* __restrict__ W,
             const float* __restrict__ bias, float* __restrict__ C,
             size_t aBatch, int aT, int t0, int tcShift)
{
    __shared__ float As[128][17];
    __shared__ float Ws[128][17];
    const int tid = threadIdx.x;
    const int tx = tid & 15, ty = tid >> 4;
    const int n0 = blockIdx.x * 128;
    const int m0 = blockIdx.y * 128;
    const int mask = (1 << tcShift) - 1;

    float acc[8][8];
#pragma unroll
    for (int i = 0; i < 8; i++)
#pragma unroll
        for (int j = 0; j < 8; j++) acc[i][j] = 0.f;

    const int lr = tid >> 1;
    const int lk = (tid & 1) * 8;
    const int rA = m0 + lr;
    const size_t aRow = (size_t)(rA >> tcShift) * aBatch + (size_t)(t0 + (rA & mask)) * (size_t)aT;
    const size_t wRow = (size_t)(n0 + lr) * (size_t)K;

    for (int k0 = 0; k0 < K; k0 += 16) {
        float4 a0 = *(const float4*)(A + aRow + k0 + lk);
        float4 a1 = *(const float4*)(A + aRow + k0 + lk + 4);
        float4 w0 = *(const float4*)(W + wRow + k0 + lk);
        float4 w1 = *(const float4*)(W + wRow + k0 + lk + 4);
        As[lr][lk+0]=a0.x; As[lr][lk+1]=a0.y; As[lr][lk+2]=a0.z; As[lr][lk+3]=a0.w;
        As[lr][lk+4]=a1.x; As[lr][lk+5]=a1.y; As[lr][lk+6]=a1.z; As[lr][lk+7]=a1.w;
        Ws[lr][lk+0]=w0.x; Ws[lr][lk+1]=w0.y; Ws[lr][lk+2]=w0.z; Ws[lr][lk+3]=w0.w;
        Ws[lr][lk+4]=w1.x; Ws[lr][lk+5]=w1.y; Ws[lr][lk+6]=w1.z; Ws[lr][lk+7]=w1.w;
        __syncthreads();
#pragma unroll
        for (int kk = 0; kk < 16; kk++) {
            float av[8], wv[8];
#pragma unroll
            for (int i = 0; i < 8; i++) av[i] = As[ty*8+i][kk];
#pragma unroll
            for (int j = 0; j < 8; j++) wv[j] = Ws[tx*8+j][kk];
#pragma unroll
            for (int i = 0; i < 8; i++)
#pragma unroll
                for (int j = 0; j < 8; j++) acc[i][j] = fmaf(av[i], wv[j], acc[i][j]);
        }
        __syncthreads();
    }
    float bv[8];
#pragma unroll
    for (int j = 0; j < 8; j++) bv[j] = bias[n0 + tx*8 + j];
#pragma unroll
    for (int i = 0; i < 8; i++) {
        const int m = m0 + ty*8 + i;
        float* cp = C + (size_t)m * G4 + n0 + tx*8;
#pragma unroll
        for (int j = 0; j < 8; j++) cp[j] = acc[i][j] + bv[j];
    }
}

#define LOAD_PIN_W(WPTR)                                                        \
    {                                                                           \
        const float* wr_ = (WPTR);                                              \
        _Pragma("unroll")                                                       \
        for (int k = 0; k < 64; k++) {                                          \
            w4[k] = *(const float4*)(wr_ + 4*k);                                \
            asm volatile("" : "+v"(w4[k].x), "+v"(w4[k].y),                     \
                              "+v"(w4[k].z), "+v"(w4[k].w));                    \
        }                                                                       \
    }

// Fused two-layer pipelined scan; 1-D grid of 192 blocks.
// bid%8 selects XCD-group; slot=bid/8 in [0,24): slot<12 -> batch=xcd,
// slot>=12 -> batch=xcd+8; role 0..3 = L0 WG g, 4..11 = L1 WG w.
// L0: WG g owns h1[g*64..g*64+64); thread owns gate row q*256+g*64+jl with its
//     full 256-float Whh0 row pinned in VGPRs. gates = Whh0@h1_{t-1} + xW0[t].
// L1: WG w owns h2[w*32..w*32+32) = 128 gate rows, 2 threads/row:
//     A-thread (tid<128) Whh1 row over h2_{t-1} (from `out`),
//     B-thread Wih1 row over h1_t (from h1buf). Pair-reduce via LDS.
// Sync: per-(b,t) counters; producers atomic_add(release), consumers poll.
__global__ __launch_bounds__(256, 1)
void lstm_fused(const float* __restrict__ Whh0, const float* __restrict__ Whh1,
                const float* __restrict__ Wih1, const float* __restrict__ b1,
                const float* __restrict__ xW,   // [BQ][TC][G4] chunk-local
                float* h1buf,                   // [BQ][TC][HH] chunk-local
                float* out,                     // [BQ][TT][HH] h2 history
                float* h1s, float* c0s, float* c1s,
                int* cnt0, int* cnt1,           // [BQ][TT] each
                int t0, int TC)
{
    const int tid = threadIdx.x;
    const int bid = blockIdx.x;
    const int xcd = bid & 7, slot = bid >> 3;
    const int b = xcd + ((slot >= 12) ? 8 : 0);
    const int role = (slot >= 12) ? slot - 12 : slot;

    __shared__ __align__(16) float hA[HH];
    __shared__ __align__(16) float hB[HH];
    __shared__ float part[128];
    __shared__ float gates[256];

    if (role < 4) {
        // ------------------------- layer 0 -------------------------
        const int g = role;
        const int q = tid >> 6;
        const int jl = tid & 63;
        const int row = q * 256 + g * 64 + jl;
        float4 w4[64];
        LOAD_PIN_W(Whh0 + (size_t)row * HH);
        float c_reg = (tid < 64) ? c0s[b*HH + g*64 + tid] : 0.f;

        for (int t = 0; t < TC; t++) {
            const int gt = t0 + t;
            const float xv = xW[((size_t)b*TC + t) * G4 + row];
            if (tid < 64) {
                if (t == 0) {
#pragma unroll
                    for (int k2 = 0; k2 < 4; k2++)
                        hA[tid + 64*k2] = h1s[b*HH + tid + 64*k2];
                } else {
                    poll_ge(cnt0 + (size_t)b*TT + gt - 1, 4);
                    const float* hp = h1buf + ((size_t)b*TC + (t-1)) * HH;
#pragma unroll
                    for (int k2 = 0; k2 < 4; k2++)
                        hA[tid + 64*k2] = __hip_atomic_load(hp + tid + 64*k2,
                                            __ATOMIC_RELAXED, __HIP_MEMORY_SCOPE_AGENT);
                }
            }
            __syncthreads();
            float ac0=0.f, ac1=0.f, ac2=0.f, ac3=0.f;
#pragma unroll
            for (int k = 0; k < 64; k++) {
                const float4 hv = *(const float4*)&hA[4*k];
                ac0 = fmaf(w4[k].x, hv.x, ac0);
                ac1 = fmaf(w4[k].y, hv.y, ac1);
                ac2 = fmaf(w4[k].z, hv.z, ac2);
                ac3 = fmaf(w4[k].w, hv.w, ac3);
            }
            const float pre = (ac0 + ac1) + (ac2 + ac3) + xv;
            gates[tid] = (q == 2) ? tanhf(pre) : sigmoidf_(pre);
            __syncthreads();
            if (tid < 64) {
                const float iv = gates[tid];
                const float fv = gates[64 + tid];
                const float gv = gates[128 + tid];
                const float ov = gates[192 + tid];
                c_reg = fmaf(fv, c_reg, iv * gv);
                const float hv = ov * tanhf(c_reg);
                __hip_atomic_store(h1buf + ((size_t)b*TC + t)*HH + g*64 + tid, hv,
                                   __ATOMIC_RELAXED, __HIP_MEMORY_SCOPE_AGENT);
                if (t == TC - 1) {
                    h1s[b*HH + g*64 + tid] = hv;
                    c0s[b*HH + g*64 + tid] = c_reg;
                }
            }
            if (tid == 0)
                __hip_atomic_fetch_add(cnt0 + (size_t)b*TT + gt, 1,
                                       __ATOMIC_RELEASE, __HIP_MEMORY_SCOPE_AGENT);
        }
    } else {
        // ------------------------- layer 1 -------------------------
        const int w = role - 4;           // 0..7
        const int r = tid & 127;
        const int isB = tid >> 7;         // 0: Whh1 over h2_prev, 1: Wih1 over h1_t
        const int q = r >> 5, jl = r & 31;
        const int row = q * 256 + w * 32 + jl;
        float4 w4[64];
        LOAD_PIN_W((isB ? Wih1 : Whh1) + (size_t)row * HH);
        const float bias = b1[row];
        float c_reg = (tid < 32) ? c1s[b*HH + w*32 + tid] : 0.f;

        for (int t = 0; t < TC; t++) {
            const int gt = t0 + t;
            if (tid < 64) {
                if (gt == 0) {
#pragma unroll
                    for (int k2 = 0; k2 < 4; k2++) hA[tid + 64*k2] = 0.f;
                } else {
                    poll_ge(cnt1 + (size_t)b*TT + gt - 1, 8);
                    const float* hp = out + ((size_t)b*TT + (gt-1)) * HH;
#pragma unroll
                    for (int k2 = 0; k2 < 4; k2++)
                        hA[tid + 64*k2] = __hip_atomic_load(hp + tid + 64*k2,
                                            __ATOMIC_RELAXED, __HIP_MEMORY_SCOPE_AGENT);
                }
            } else if (tid < 128) {
                const int l = tid - 64;
                poll_ge(cnt0 + (size_t)b*TT + gt, 4);
                const float* hp = h1buf + ((size_t)b*TC + t) * HH;
#pragma unroll
                for (int k2 = 0; k2 < 4; k2++)
                    hB[l + 64*k2] = __hip_atomic_load(hp + l + 64*k2,
                                        __ATOMIC_RELAXED, __HIP_MEMORY_SCOPE_AGENT);
            }
            __syncthreads();
            const float* hsrc = isB ? hB : hA;
            float ac0=0.f, ac1=0.f, ac2=0.f, ac3=0.f;
#pragma unroll
            for (int k = 0; k < 64; k++) {
                const float4 hv = *(const float4*)&hsrc[4*k];
                ac0 = fmaf(w4[k].x, hv.x, ac0);
                ac1 = fmaf(w4[k].y, hv.y, ac1);
                ac2 = fmaf(w4[k].z, hv.z, ac2);
                ac3 = fmaf(w4[k].w, hv.w, ac3);
            }
            const float dot = (ac0 + ac1) + (ac2 + ac3);
            if (isB) part[r] = dot;
            __syncthreads();
            if (!isB) {
                const float pre = dot + part[r] + bias;
                gates[r] = (q == 2) ? tanhf(pre) : sigmoidf_(pre);
            }
            __syncthreads();
            if (tid < 32) {
                const float iv = gates[tid];
                const float fv = gates[32 + tid];
                const float gv = gates[64 + tid];
                const float ov = gates[96 + tid];
                c_reg = fmaf(fv, c_reg, iv * gv);
                const float hv = ov * tanhf(c_reg);
                __hip_atomic_store(out + ((size_t)b*TT + gt)*HH + w*32 + tid, hv,
                                   __ATOMIC_RELAXED, __HIP_MEMORY_SCOPE_AGENT);
                if (t == TC - 1) c1s[b*HH + w*32 + tid] = c_reg;
            }
            if (tid == 0)
                __hip_atomic_fetch_add(cnt1 + (size_t)b*TT + gt, 1,
                                       __ATOMIC_RELEASE, __HIP_MEMORY_SCOPE_AGENT);
        }
    }
}

extern "C" void kernel_launch(void* const* d_in, const int* in_sizes, int n_in,
                              void* d_out, int out_size, void* d_ws, size_t ws_size,
                              hipStream_t stream) {
    (void)in_sizes; (void)n_in; (void)out_size;
    const float* x    = (const float*)d_in[0];
    const float* Wih0 = (const float*)d_in[1];
    const float* Whh0 = (const float*)d_in[2];
    const float* b0   = (const float*)d_in[3];
    const float* Wih1 = (const float*)d_in[4];
    const float* Whh1 = (const float*)d_in[5];
    const float* b1   = (const float*)d_in[6];
    float* out = (float*)d_out;

    // ---- workspace carve ----
    char* ws = (char*)d_ws;
    float* h1s = (float*)ws;                 // [16][256]
    float* c0s = h1s + BQ*HH;
    float* c1s = c0s + BQ*HH;
    int*   cnt0 = (int*)(c1s + BQ*HH);       // [16][4096]
    int*   cnt1 = cnt0 + (size_t)BQ*TT;
    float* bulk = (float*)(cnt1 + (size_t)BQ*TT);
    const size_t fixedBytes = (size_t)((char*)bulk - ws);

    int TC = 4096;
    while (TC > 64 && fixedBytes + (size_t)BQ * TC * (HH + G4) * 4 > ws_size) TC >>= 1;
    const int tcShift = __builtin_ctz((unsigned)TC);

    float* h1buf = bulk;                      // [16][TC][256]
    float* xWb = h1buf + (size_t)BQ*TC*HH;    // [16][TC][1024]

    hipMemsetAsync(ws, 0, fixedBytes, stream);

    for (int t0 = 0; t0 < TT; t0 += TC) {
        dim3 g0(G4/128, (BQ*TC)/128);
        gemm_xw<II><<<g0, 256, 0, stream>>>(x, Wih0, b0, xWb,
                                            (size_t)TT*II, II, t0, tcShift);
        lstm_fused<<<192, 256, 0, stream>>>(Whh0, Whh1, Wih1, b1,
                                            xWb, h1buf, out,
                                            h1s, c0s, c1s,
                                            cnt0, cnt1, t0, TC);
    }
}

// Round 4
// 23134.056 us; speedup vs baseline: 1.4630x; 1.3208x over previous
//
#include <hip/hip_runtime.h>
#include <stdint.h>

#define BQ 16      // batch
#define TT 4096    // timesteps
#define II 128     // input features
#define HH 256     // hidden
#define G4 1024    // 4*H

__device__ __forceinline__ float sigmoidf_(float x) { return 1.0f / (1.0f + __expf(-x)); }

__device__ __forceinline__ void poll_ge(const int* p, int target) {
    // all lanes load the same word -> one request; uniform loop
    while (__hip_atomic_load(p, __ATOMIC_ACQUIRE, __HIP_MEMORY_SCOPE_AGENT) < target)
        __builtin_amdgcn_s_sleep(1);
}

// C[m][n] = sum_k A_row(m)[k] * W[n][k] + bias[n]
template<int K>
__global__ __launch_bounds__(256, 2)
void gemm_xw(const float* __restrict__ A, const float* __restrict__ W,
             const float* __restrict__ bias, float* __restrict__ C,
             size_t aBatch, int aT, int t0, int tcShift)
{
    __shared__ float As[128][17];
    __shared__ float Ws[128][17];
    const int tid = threadIdx.x;
    const int tx = tid & 15, ty = tid >> 4;
    const int n0 = blockIdx.x * 128;
    const int m0 = blockIdx.y * 128;
    const int mask = (1 << tcShift) - 1;

    float acc[8][8];
#pragma unroll
    for (int i = 0; i < 8; i++)
#pragma unroll
        for (int j = 0; j < 8; j++) acc[i][j] = 0.f;

    const int lr = tid >> 1;
    const int lk = (tid & 1) * 8;
    const int rA = m0 + lr;
    const size_t aRow = (size_t)(rA >> tcShift) * aBatch + (size_t)(t0 + (rA & mask)) * (size_t)aT;
    const size_t wRow = (size_t)(n0 + lr) * (size_t)K;

    for (int k0 = 0; k0 < K; k0 += 16) {
        float4 a0 = *(const float4*)(A + aRow + k0 + lk);
        float4 a1 = *(const float4*)(A + aRow + k0 + lk + 4);
        float4 w0 = *(const float4*)(W + wRow + k0 + lk);
        float4 w1 = *(const float4*)(W + wRow + k0 + lk + 4);
        As[lr][lk+0]=a0.x; As[lr][lk+1]=a0.y; As[lr][lk+2]=a0.z; As[lr][lk+3]=a0.w;
        As[lr][lk+4]=a1.x; As[lr][lk+5]=a1.y; As[lr][lk+6]=a1.z; As[lr][lk+7]=a1.w;
        Ws[lr][lk+0]=w0.x; Ws[lr][lk+1]=w0.y; Ws[lr][lk+2]=w0.z; Ws[lr][lk+3]=w0.w;
        Ws[lr][lk+4]=w1.x; Ws[lr][lk+5]=w1.y; Ws[lr][lk+6]=w1.z; Ws[lr][lk+7]=w1.w;
        __syncthreads();
#pragma unroll
        for (int kk = 0; kk < 16; kk++) {
            float av[8], wv[8];
#pragma unroll
            for (int i = 0; i < 8; i++) av[i] = As[ty*8+i][kk];
#pragma unroll
            for (int j = 0; j < 8; j++) wv[j] = Ws[tx*8+j][kk];
#pragma unroll
            for (int i = 0; i < 8; i++)
#pragma unroll
                for (int j = 0; j < 8; j++) acc[i][j] = fmaf(av[i], wv[j], acc[i][j]);
        }
        __syncthreads();
    }
    float bv[8];
#pragma unroll
    for (int j = 0; j < 8; j++) bv[j] = bias[n0 + tx*8 + j];
#pragma unroll
    for (int i = 0; i < 8; i++) {
        const int m = m0 + ty*8 + i;
        float* cp = C + (size_t)m * G4 + n0 + tx*8;
#pragma unroll
        for (int j = 0; j < 8; j++) cp[j] = acc[i][j] + bv[j];
    }
}

// pin 32 float4 (128 floats) in VGPRs; asm def cannot be rematerialized
#define LOAD_PIN_W32(WPTR)                                                      \
    {                                                                           \
        const float* wr_ = (WPTR);                                              \
        _Pragma("unroll")                                                       \
        for (int k = 0; k < 32; k++) {                                          \
            w4[k] = *(const float4*)(wr_ + 4*k);                                \
            asm volatile("" : "+v"(w4[k].x), "+v"(w4[k].y),                     \
                              "+v"(w4[k].z), "+v"(w4[k].w));                    \
        }                                                                       \
    }

// Fused two-layer pipelined scan; 192 blocks x 512 threads (1 WG/CU).
// bid%8 = XCD-group, slot=bid/8: slot<12 -> b=xcd, else b=xcd+8; role=slot%12.
// role 0..3  = L0 WG g: owns h1[g*64..+64) = 256 gate rows; 2 thr/row
//              (r=tid&255, half=tid>>8 selects K-half of Whh0 row; 128 floats
//              pinned in VGPRs). LDS pair-reduce; gates += xW0[t] (has b0).
// role 4..11 = L1 WG w: owns h2[w*32..+32) = 128 gate rows; 4 thr/row
//              (r=tid&127, seg=tid>>7: seg0,1 = Whh1 halves over h2_{t-1},
//              seg2,3 = Wih1 halves over h1_t). LDS 3-way reduce + b1.
// Sync: per-(b,t) counters, producers atomic_add(release), one wave polls.
__global__ __launch_bounds__(512, 1)
void lstm_fused(const float* __restrict__ Whh0, const float* __restrict__ Whh1,
                const float* __restrict__ Wih1, const float* __restrict__ b1,
                const float* __restrict__ xW,   // [BQ][TC][G4] chunk-local
                float* h1buf,                   // [BQ][TC][HH] chunk-local
                float* out,                     // [BQ][TT][HH] h2 history
                float* h1s, float* c0s, float* c1s,
                int* cnt0, int* cnt1,           // [BQ][TT] each
                int t0, int TC)
{
    const int tid = threadIdx.x;
    const int bid = blockIdx.x;
    const int xcd = bid & 7, slot = bid >> 3;
    const int b = xcd + ((slot >= 12) ? 8 : 0);
    const int role = (slot >= 12) ? slot - 12 : slot;

    __shared__ __align__(16) float hA[HH];
    __shared__ __align__(16) float hB[HH];
    __shared__ float part[384];
    __shared__ float gates[256];

    if (role < 4) {
        // ------------------------- layer 0 -------------------------
        const int g = role;
        const int r = tid & 255;          // row within WG's 256
        const int half = tid >> 8;        // K-half
        const int q = r >> 6, jl = r & 63;
        const int row = q * 256 + g * 64 + jl;
        float4 w4[32];
        LOAD_PIN_W32(Whh0 + (size_t)row * HH + half * 128);
        float c_reg = (tid < 64) ? c0s[b*HH + g*64 + tid] : 0.f;

        for (int t = 0; t < TC; t++) {
            const int gt = t0 + t;
            float xv = 0.f;
            if (!half) xv = xW[((size_t)b*TC + t) * G4 + row];
            if (tid < 64) {
                if (t == 0) {
#pragma unroll
                    for (int k2 = 0; k2 < 4; k2++)
                        hA[tid + 64*k2] = h1s[b*HH + tid + 64*k2];
                } else {
                    poll_ge(cnt0 + (size_t)b*TT + gt - 1, 4);
                    const float* hp = h1buf + ((size_t)b*TC + (t-1)) * HH;
#pragma unroll
                    for (int k2 = 0; k2 < 4; k2++)
                        hA[tid + 64*k2] = __hip_atomic_load(hp + tid + 64*k2,
                                            __ATOMIC_RELAXED, __HIP_MEMORY_SCOPE_AGENT);
                }
            }
            __syncthreads();
            const float* hsrc = &hA[half * 128];
            float ac0=0.f, ac1=0.f, ac2=0.f, ac3=0.f;
#pragma unroll
            for (int k = 0; k < 32; k++) {
                const float4 hv = *(const float4*)&hsrc[4*k];
                ac0 = fmaf(w4[k].x, hv.x, ac0);
                ac1 = fmaf(w4[k].y, hv.y, ac1);
                ac2 = fmaf(w4[k].z, hv.z, ac2);
                ac3 = fmaf(w4[k].w, hv.w, ac3);
            }
            const float dot = (ac0 + ac1) + (ac2 + ac3);
            if (half) part[r] = dot;
            __syncthreads();
            if (!half) {
                const float pre = dot + part[r] + xv;
                gates[r] = (q == 2) ? tanhf(pre) : sigmoidf_(pre);
            }
            __syncthreads();
            if (tid < 64) {
                const float iv = gates[tid];
                const float fv = gates[64 + tid];
                const float gv = gates[128 + tid];
                const float ov = gates[192 + tid];
                c_reg = fmaf(fv, c_reg, iv * gv);
                const float hv = ov * tanhf(c_reg);
                __hip_atomic_store(h1buf + ((size_t)b*TC + t)*HH + g*64 + tid, hv,
                                   __ATOMIC_RELAXED, __HIP_MEMORY_SCOPE_AGENT);
                if (t == TC - 1) {
                    h1s[b*HH + g*64 + tid] = hv;
                    c0s[b*HH + g*64 + tid] = c_reg;
                }
            }
            if (tid == 0)
                __hip_atomic_fetch_add(cnt0 + (size_t)b*TT + gt, 1,
                                       __ATOMIC_RELEASE, __HIP_MEMORY_SCOPE_AGENT);
        }
    } else {
        // ------------------------- layer 1 -------------------------
        const int w = role - 4;           // 0..7
        const int r = tid & 127;          // row within WG's 128
        const int seg = tid >> 7;         // 0,1: Whh1 halves; 2,3: Wih1 halves
        const int q = r >> 5, jl = r & 31;
        const int row = q * 256 + w * 32 + jl;
        float4 w4[32];
        LOAD_PIN_W32(((seg < 2) ? Whh1 : Wih1) + (size_t)row * HH + (seg & 1) * 128);
        const float bias = (seg == 0) ? b1[row] : 0.f;
        float c_reg = (tid < 32) ? c1s[b*HH + w*32 + tid] : 0.f;

        for (int t = 0; t < TC; t++) {
            const int gt = t0 + t;
            if (tid < 64) {
                // wave 0: stage h2_{t-1}
                if (gt == 0) {
#pragma unroll
                    for (int k2 = 0; k2 < 4; k2++) hA[tid + 64*k2] = 0.f;
                } else {
                    poll_ge(cnt1 + (size_t)b*TT + gt - 1, 8);
                    const float* hp = out + ((size_t)b*TT + (gt-1)) * HH;
#pragma unroll
                    for (int k2 = 0; k2 < 4; k2++)
                        hA[tid + 64*k2] = __hip_atomic_load(hp + tid + 64*k2,
                                            __ATOMIC_RELAXED, __HIP_MEMORY_SCOPE_AGENT);
                }
            } else if (tid < 128) {
                // wave 1: stage h1_t
                const int l = tid - 64;
                poll_ge(cnt0 + (size_t)b*TT + gt, 4);
                const float* hp = h1buf + ((size_t)b*TC + t) * HH;
#pragma unroll
                for (int k2 = 0; k2 < 4; k2++)
                    hB[l + 64*k2] = __hip_atomic_load(hp + l + 64*k2,
                                        __ATOMIC_RELAXED, __HIP_MEMORY_SCOPE_AGENT);
            }
            __syncthreads();
            const float* hsrc = (seg < 2) ? &hA[(seg & 1) * 128] : &hB[(seg & 1) * 128];
            float ac0=0.f, ac1=0.f, ac2=0.f, ac3=0.f;
#pragma unroll
            for (int k = 0; k < 32; k++) {
                const float4 hv = *(const float4*)&hsrc[4*k];
                ac0 = fmaf(w4[k].x, hv.x, ac0);
                ac1 = fmaf(w4[k].y, hv.y, ac1);
                ac2 = fmaf(w4[k].z, hv.z, ac2);
                ac3 = fmaf(w4[k].w, hv.w, ac3);
            }
            const float dot = (ac0 + ac1) + (ac2 + ac3);
            if (seg) part[(seg - 1) * 128 + r] = dot;
            __syncthreads();
            if (!seg) {
                const float pre = dot + part[r] + part[128 + r] + part[256 + r] + bias;
                gates[r] = (q == 2) ? tanhf(pre) : sigmoidf_(pre);
            }
            __syncthreads();
            if (tid < 32) {
                const float iv = gates[tid];
                const float fv = gates[32 + tid];
                const float gv = gates[64 + tid];
                const float ov = gates[96 + tid];
                c_reg = fmaf(fv, c_reg, iv * gv);
                const float hv = ov * tanhf(c_reg);
                __hip_atomic_store(out + ((size_t)b*TT + gt)*HH + w*32 + tid, hv,
                                   __ATOMIC_RELAXED, __HIP_MEMORY_SCOPE_AGENT);
                if (t == TC - 1) c1s[b*HH + w*32 + tid] = c_reg;
            }
            if (tid == 0)
                __hip_atomic_fetch_add(cnt1 + (size_t)b*TT + gt, 1,
                                       __ATOMIC_RELEASE, __HIP_MEMORY_SCOPE_AGENT);
        }
    }
}

extern "C" void kernel_launch(void* const* d_in, const int* in_sizes, int n_in,
                              void* d_out, int out_size, void* d_ws, size_t ws_size,
                              hipStream_t stream) {
    (void)in_sizes; (void)n_in; (void)out_size;
    const float* x    = (const float*)d_in[0];
    const float* Wih0 = (const float*)d_in[1];
    const float* Whh0 = (const float*)d_in[2];
    const float* b0   = (const float*)d_in[3];
    const float* Wih1 = (const float*)d_in[4];
    const float* Whh1 = (const float*)d_in[5];
    const float* b1   = (const float*)d_in[6];
    float* out = (float*)d_out;

    // ---- workspace carve ----
    char* ws = (char*)d_ws;
    float* h1s = (float*)ws;                 // [16][256]
    float* c0s = h1s + BQ*HH;
    float* c1s = c0s + BQ*HH;
    int*   cnt0 = (int*)(c1s + BQ*HH);       // [16][4096]
    int*   cnt1 = cnt0 + (size_t)BQ*TT;
    float* bulk = (float*)(cnt1 + (size_t)BQ*TT);
    const size_t fixedBytes = (size_t)((char*)bulk - ws);

    int TC = 4096;
    while (TC > 64 && fixedBytes + (size_t)BQ * TC * (HH + G4) * 4 > ws_size) TC >>= 1;
    const int tcShift = __builtin_ctz((unsigned)TC);

    float* h1buf = bulk;                      // [16][TC][256]
    float* xWb = h1buf + (size_t)BQ*TC*HH;    // [16][TC][1024]

    hipMemsetAsync(ws, 0, fixedBytes, stream);

    for (int t0 = 0; t0 < TT; t0 += TC) {
        dim3 g0(G4/128, (BQ*TC)/128);
        gemm_xw<II><<<g0, 256, 0, stream>>>(x, Wih0, b0, xWb,
                                            (size_t)TT*II, II, t0, tcShift);
        lstm_fused<<<192, 512, 0, stream>>>(Whh0, Whh1, Wih1, b1,
                                            xWb, h1buf, out,
                                            h1s, c0s, c1s,
                                            cnt0, cnt1, t0, TC);
    }
}